// Round 16
// baseline (59.498 us; speedup 1.0000x reference)
//
#include <hip/hip_runtime.h>

namespace {
constexpr int BATCH = 512;
constexpr int SEQL  = 512;
constexpr int HID   = 256;
constexpr int MORPH = 24;
constexpr float NEGV = -1.0e9f;
constexpr int NTHR  = 512;    // 8 waves; ~5.7 KB LDS
constexpr int NWAVE = 8;
}

typedef float f4 __attribute__((ext_vector_type(4)));

__device__ __forceinline__ unsigned okey(float f) {
    unsigned u = __float_as_uint(f);
    return u ^ (unsigned)(((int)u >> 31) | 0x80000000);
}

// One block per b; 512 thr = 8 waves.
// P1: keys (4 rows/wave/iter, 16-lane row slices). P2: radix select -> c2m+sep.
// P3: bpm one-hot FIRST (store stream drains under P4's load latency).
// P4: menc via LPT work-stealing (longest morpheme first) with 8 acc chains.
extern "C" __global__ __launch_bounds__(NTHR)
void morphseg_kernel(const float* __restrict__ we,    // [B, L, H]
                     const int*   __restrict__ wlen,  // [B]
                     const int*   __restrict__ nmorph,// [B]
                     const float* __restrict__ Wv,    // [H]
                     const float* __restrict__ bias,  // [1]
                     float* __restrict__ out)         // menc [B*M*H] then bpm [B*L*M]
{
    const int b    = blockIdx.x;
    const int tid  = threadIdx.x;
    const int lane = tid & 63;
    const int wave = tid >> 6;

    __shared__ unsigned s_keys[SEQL];                // 2 KB
    __shared__ int s_hist[256];                      // 1 KB
    __shared__ int s_c2m[SEQL];                      // 2 KB
    __shared__ int s_sep[32];
    __shared__ int s_msize[MORPH], s_morder[MORPH];
    __shared__ int s_next;
    __shared__ unsigned long long s_eqm[8], s_ind[8];
    __shared__ unsigned s_p, s_T;
    __shared__ int s_Kr, s_KrF, s_done;

    const int wl = wlen[b];
    const int nm = nmorph[b];
    const int K  = nm - 1;
    const float b0 = bias[0];
    const float* __restrict__ werow = we + (size_t)b * (SEQL * HID);
    const unsigned KEYNEG = okey(NEGV);

    // ---- init
    s_keys[tid] = KEYNEG;          // NTHR == SEQL
    if (tid == 0) { s_p = 0u; s_Kr = K; s_done = 0; s_next = 0; }
    __syncthreads();

    // ---- Phase 1: keys. 4 rows per wave per iter; lane = 16*rg + hg.
    {
        const int hg = lane & 15;          // h-slice: floats [hg*16, hg*16+16)
        const int rg = lane >> 4;          // row within the 4-row group
        const f4* __restrict__ W4 = reinterpret_cast<const f4*>(Wv);
        const f4 w0 = W4[hg * 4 + 0], w1 = W4[hg * 4 + 1];
        const f4 w2 = W4[hg * 4 + 2], w3 = W4[hg * 4 + 3];
        const int nvalid = wl - 1;
        for (int l0 = wave * 4; l0 < nvalid; l0 += NWAVE * 4) {
            const int row = l0 + rg;
            if (row < nvalid) {            // uniform per 16-lane group
                const f4* __restrict__ rp =
                    reinterpret_cast<const f4*>(werow + (size_t)row * HID);
                const f4 v0 = rp[hg * 4 + 0], v1 = rp[hg * 4 + 1];
                const f4 v2 = rp[hg * 4 + 2], v3 = rp[hg * 4 + 3];
                const f4 p = v0 * w0 + v1 * w1 + v2 * w2 + v3 * w3;
                float d = (p[0] + p[1]) + (p[2] + p[3]);
                #pragma unroll
                for (int off = 1; off < 16; off <<= 1)
                    d += __shfl_xor(d, off, 64);
                if (hg == 0) s_keys[row] = okey(d + b0);
            }
        }
    }
    __syncthreads();

    // ---- Phase 2: radix select, MSB-first, early exit on exact boundary
    int done = 0;
    for (int pass = 0; pass < 4 && !done; ++pass) {
        const int shift = 24 - 8 * pass;
        if (tid < 256) s_hist[tid] = 0;
        __syncthreads();
        {
            const unsigned k = s_keys[tid];
            if (pass == 0 || (k >> (shift + 8)) == (s_p >> (shift + 8)))
                atomicAdd(&s_hist[(k >> shift) & 255], 1);
        }
        __syncthreads();
        if (wave == 0) {
            const int v0 = lane * 4;
            const int h0 = s_hist[v0], h1 = s_hist[v0 + 1];
            const int h2 = s_hist[v0 + 2], h3 = s_hist[v0 + 3];
            const int local = h0 + h1 + h2 + h3;
            int T = local;
            #pragma unroll
            for (int off = 1; off < 64; off <<= 1) {
                const int u = __shfl_down(T, off, 64);
                if (lane + off < 64) T += u;
            }
            const int A  = T - local;
            const int S3 = A + h3, S2 = S3 + h2, S1 = S2 + h1, S0 = S1 + h0;
            const int Kr = s_Kr;
            const unsigned p = s_p;
            int v = -1, Sv = 0, Sv1 = 0;
            if (A  < Kr && Kr <= S3) { v = v0 + 3; Sv = S3; Sv1 = A;  }
            if (S3 < Kr && Kr <= S2) { v = v0 + 2; Sv = S2; Sv1 = S3; }
            if (S2 < Kr && Kr <= S1) { v = v0 + 1; Sv = S1; Sv1 = S2; }
            if (S1 < Kr && Kr <= S0) { v = v0 + 0; Sv = S0; Sv1 = S1; }
            if (v >= 0) {
                const unsigned pv = p | ((unsigned)v << shift);
                if (Sv == Kr)        { s_T = pv - 1u; s_KrF = 0;        s_done = 1; }
                else if (shift == 0) { s_T = pv;      s_KrF = Kr - Sv1; s_done = 1; }
                else                 { s_p = pv;      s_Kr = Kr - Sv1; }
            }
        }
        __syncthreads();
        done = s_done;
    }

    // ---- separator flags (stable ties) -> c2m + sep list
    const unsigned Tf = s_T;
    const int KrF = s_KrF;
    const unsigned k = s_keys[tid];
    const bool gt = (k > Tf);
    const bool eq = (k == Tf);
    const unsigned long long eb = __ballot(eq);
    if (lane == 0) s_eqm[wave] = eb;
    __syncthreads();

    auto prefix8 = [&](const unsigned long long* w8, int pos) -> int {
        const int wi = pos >> 6;
        const unsigned long long lowmask = (1ull << (pos & 63)) - 1ull;
        int r = 0;
        #pragma unroll
        for (int q2 = 0; q2 < 8; ++q2) {
            const unsigned long long w = w8[q2];
            r += (q2 < wi) ? __popcll(w) : ((q2 == wi) ? __popcll(w & lowmask) : 0);
        }
        return r;
    };

    const int f = gt || (eq && prefix8(s_eqm, tid) < KrF);
    const unsigned long long fb = __ballot(f);
    if (lane == 0) s_ind[wave] = fb;
    __syncthreads();
    {
        const int cnt = prefix8(s_ind, tid);
        s_c2m[tid] = cnt;
        if (f) s_sep[cnt] = tid;     // cnt in [0,K): unique per separator
    }
    __syncthreads();

    // ---- morpheme sizes + LPT order (desc size, stable)
    if (tid < MORPH) {
        const int m  = tid;
        int sz = 0;
        if (m < nm) {
            const int lo = (m == 0) ? 0 : s_sep[m - 1] + 1;
            const int hi = (m < K) ? s_sep[m] : wl - 1;
            sz = hi - lo + 1;
        }
        s_msize[m] = sz;
    }
    __syncthreads();
    if (tid < MORPH) {
        const int sz = s_msize[tid];
        int r = 0;
        for (int j = 0; j < MORPH; ++j) {
            const int sj = s_msize[j];
            r += (int)(sj > sz) | ((int)(sj == sz) & (int)(j < tid));
        }
        s_morder[r] = tid;
    }
    __syncthreads();

    // ---- Phase 3: bpm one-hot FIRST (pure store stream, no load deps)
    {
        float* __restrict__ bpm = out + (size_t)BATCH * MORPH * HID + (size_t)b * (SEQL * MORPH);
        for (int v = tid; v < SEQL * MORPH / 4; v += NTHR) {
            const int l  = v / 6;
            const int qv = v - l * 6;
            const int c  = s_c2m[l];
            const int mb = qv * 4;
            const bool valid = (l < wl);
            f4 o;
            o.x = (valid && c == mb + 0 && mb + 0 < nm) ? 1.0f : 0.0f;
            o.y = (valid && c == mb + 1 && mb + 1 < nm) ? 1.0f : 0.0f;
            o.z = (valid && c == mb + 2 && mb + 2 < nm) ? 1.0f : 0.0f;
            o.w = (valid && c == mb + 3 && mb + 3 < nm) ? 1.0f : 0.0f;
            __builtin_nontemporal_store(o, reinterpret_cast<f4*>(bpm) + v);
        }
    }

    // ---- Phase 4: menc, LPT work-stealing, 8 independent chains.
    // Deterministic: each morpheme's sum order is fixed by the loop structure,
    // independent of which wave executes it.
    for (;;) {
        int idx = 0;
        if (lane == 0) idx = atomicAdd(&s_next, 1);
        idx = __shfl(idx, 0, 64);
        if (idx >= MORPH) break;
        const int m = s_morder[idx];

        f4 t = {0.f, 0.f, 0.f, 0.f};
        if (m < nm) {
            const int lo = (m == 0) ? 0 : s_sep[m - 1] + 1;
            const int hi = (m < K) ? s_sep[m] : wl - 1;   // inclusive
            f4 a0 = {0.f,0.f,0.f,0.f}, a1 = {0.f,0.f,0.f,0.f};
            f4 a2 = {0.f,0.f,0.f,0.f}, a3 = {0.f,0.f,0.f,0.f};
            f4 a4 = {0.f,0.f,0.f,0.f}, a5 = {0.f,0.f,0.f,0.f};
            f4 a6 = {0.f,0.f,0.f,0.f}, a7 = {0.f,0.f,0.f,0.f};
            int l = lo;
            for (; l + 7 <= hi; l += 8) {
                a0 += reinterpret_cast<const f4*>(werow + (size_t)(l    ) * HID)[lane];
                a1 += reinterpret_cast<const f4*>(werow + (size_t)(l + 1) * HID)[lane];
                a2 += reinterpret_cast<const f4*>(werow + (size_t)(l + 2) * HID)[lane];
                a3 += reinterpret_cast<const f4*>(werow + (size_t)(l + 3) * HID)[lane];
                a4 += reinterpret_cast<const f4*>(werow + (size_t)(l + 4) * HID)[lane];
                a5 += reinterpret_cast<const f4*>(werow + (size_t)(l + 5) * HID)[lane];
                a6 += reinterpret_cast<const f4*>(werow + (size_t)(l + 6) * HID)[lane];
                a7 += reinterpret_cast<const f4*>(werow + (size_t)(l + 7) * HID)[lane];
            }
            for (; l + 1 <= hi; l += 2) {
                a0 += reinterpret_cast<const f4*>(werow + (size_t)(l    ) * HID)[lane];
                a1 += reinterpret_cast<const f4*>(werow + (size_t)(l + 1) * HID)[lane];
            }
            if (l <= hi)
                a0 += reinterpret_cast<const f4*>(werow + (size_t)l * HID)[lane];
            t = ((a0 + a1) + (a2 + a3)) + ((a4 + a5) + (a6 + a7));
        }
        __builtin_nontemporal_store(
            t, reinterpret_cast<f4*>(out + (size_t)b * (MORPH * HID) + (size_t)m * HID) + lane);
    }
}

extern "C" void kernel_launch(void* const* d_in, const int* in_sizes, int n_in,
                              void* d_out, int out_size, void* d_ws, size_t ws_size,
                              hipStream_t stream) {
    const float* we     = (const float*)d_in[0];
    const int*   wlen   = (const int*)d_in[1];
    const int*   nmorph = (const int*)d_in[2];
    const float* Wv     = (const float*)d_in[3];
    const float* bias   = (const float*)d_in[4];
    float* out = (float*)d_out;

    morphseg_kernel<<<dim3(BATCH), dim3(NTHR), 0, stream>>>(
        we, wlen, nmorph, Wv, bias, out);
}

// Round 17
// 55.804 us; speedup vs baseline: 1.0662x; 1.0662x over previous
//
#include <hip/hip_runtime.h>

namespace {
constexpr int BATCH = 512;
constexpr int SEQL  = 512;
constexpr int HID   = 256;
constexpr int MORPH = 24;
constexpr float NEGV = -1.0e9f;
constexpr int NTHR  = 512;    // 8 waves; ~5.5 KB LDS
constexpr int NWAVE = 8;
}

typedef float f4 __attribute__((ext_vector_type(4)));

__device__ __forceinline__ unsigned okey(float f) {
    unsigned u = __float_as_uint(f);
    return u ^ (unsigned)(((int)u >> 31) | 0x80000000);
}

// One block per b; 512 thr = 8 waves.
// P1: keys (4 rows/wave/iter, 16-lane row slices). P2: radix select -> c2m+sep.
// P3: bpm one-hot FIRST (dependency-free NT store stream drains under P4's
//     load latency). P4: menc wave-per-morpheme with 4 accumulator chains.
// (Round-15 configuration: best measured at 55.3 us. 8-chain/LPT variant
//  regressed to 59.5 via occupancy loss — 4 chains is the sweet spot.)
extern "C" __global__ __launch_bounds__(NTHR)
void morphseg_kernel(const float* __restrict__ we,    // [B, L, H]
                     const int*   __restrict__ wlen,  // [B]
                     const int*   __restrict__ nmorph,// [B]
                     const float* __restrict__ Wv,    // [H]
                     const float* __restrict__ bias,  // [1]
                     float* __restrict__ out)         // menc [B*M*H] then bpm [B*L*M]
{
    const int b    = blockIdx.x;
    const int tid  = threadIdx.x;
    const int lane = tid & 63;
    const int wave = tid >> 6;

    __shared__ unsigned s_keys[SEQL];                // 2 KB
    __shared__ int s_hist[256];                      // 1 KB
    __shared__ int s_c2m[SEQL];                      // 2 KB
    __shared__ int s_sep[32];
    __shared__ unsigned long long s_eqm[8], s_ind[8];
    __shared__ unsigned s_p, s_T;
    __shared__ int s_Kr, s_KrF, s_done;

    const int wl = wlen[b];
    const int nm = nmorph[b];
    const int K  = nm - 1;
    const float b0 = bias[0];
    const float* __restrict__ werow = we + (size_t)b * (SEQL * HID);
    const unsigned KEYNEG = okey(NEGV);

    // ---- init
    s_keys[tid] = KEYNEG;          // NTHR == SEQL
    if (tid == 0) { s_p = 0u; s_Kr = K; s_done = 0; }
    __syncthreads();

    // ---- Phase 1: keys. 4 rows per wave per iter; lane = 16*rg + hg.
    {
        const int hg = lane & 15;          // h-slice: floats [hg*16, hg*16+16)
        const int rg = lane >> 4;          // row within the 4-row group
        const f4* __restrict__ W4 = reinterpret_cast<const f4*>(Wv);
        const f4 w0 = W4[hg * 4 + 0], w1 = W4[hg * 4 + 1];
        const f4 w2 = W4[hg * 4 + 2], w3 = W4[hg * 4 + 3];
        const int nvalid = wl - 1;
        for (int l0 = wave * 4; l0 < nvalid; l0 += NWAVE * 4) {
            const int row = l0 + rg;
            if (row < nvalid) {            // uniform per 16-lane group
                const f4* __restrict__ rp =
                    reinterpret_cast<const f4*>(werow + (size_t)row * HID);
                const f4 v0 = rp[hg * 4 + 0], v1 = rp[hg * 4 + 1];
                const f4 v2 = rp[hg * 4 + 2], v3 = rp[hg * 4 + 3];
                const f4 p = v0 * w0 + v1 * w1 + v2 * w2 + v3 * w3;
                float d = (p[0] + p[1]) + (p[2] + p[3]);
                #pragma unroll
                for (int off = 1; off < 16; off <<= 1)
                    d += __shfl_xor(d, off, 64);
                if (hg == 0) s_keys[row] = okey(d + b0);
            }
        }
    }
    __syncthreads();

    // ---- Phase 2: radix select, MSB-first, early exit on exact boundary
    int done = 0;
    for (int pass = 0; pass < 4 && !done; ++pass) {
        const int shift = 24 - 8 * pass;
        if (tid < 256) s_hist[tid] = 0;
        __syncthreads();
        {
            const unsigned k = s_keys[tid];
            if (pass == 0 || (k >> (shift + 8)) == (s_p >> (shift + 8)))
                atomicAdd(&s_hist[(k >> shift) & 255], 1);
        }
        __syncthreads();
        if (wave == 0) {
            const int v0 = lane * 4;
            const int h0 = s_hist[v0], h1 = s_hist[v0 + 1];
            const int h2 = s_hist[v0 + 2], h3 = s_hist[v0 + 3];
            const int local = h0 + h1 + h2 + h3;
            int T = local;
            #pragma unroll
            for (int off = 1; off < 64; off <<= 1) {
                const int u = __shfl_down(T, off, 64);
                if (lane + off < 64) T += u;
            }
            const int A  = T - local;
            const int S3 = A + h3, S2 = S3 + h2, S1 = S2 + h1, S0 = S1 + h0;
            const int Kr = s_Kr;
            const unsigned p = s_p;
            int v = -1, Sv = 0, Sv1 = 0;
            if (A  < Kr && Kr <= S3) { v = v0 + 3; Sv = S3; Sv1 = A;  }
            if (S3 < Kr && Kr <= S2) { v = v0 + 2; Sv = S2; Sv1 = S3; }
            if (S2 < Kr && Kr <= S1) { v = v0 + 1; Sv = S1; Sv1 = S2; }
            if (S1 < Kr && Kr <= S0) { v = v0 + 0; Sv = S0; Sv1 = S1; }
            if (v >= 0) {
                const unsigned pv = p | ((unsigned)v << shift);
                if (Sv == Kr)        { s_T = pv - 1u; s_KrF = 0;        s_done = 1; }
                else if (shift == 0) { s_T = pv;      s_KrF = Kr - Sv1; s_done = 1; }
                else                 { s_p = pv;      s_Kr = Kr - Sv1; }
            }
        }
        __syncthreads();
        done = s_done;
    }

    // ---- separator flags (stable ties) -> c2m + sep list
    const unsigned Tf = s_T;
    const int KrF = s_KrF;
    const unsigned k = s_keys[tid];
    const bool gt = (k > Tf);
    const bool eq = (k == Tf);
    const unsigned long long eb = __ballot(eq);
    if (lane == 0) s_eqm[wave] = eb;
    __syncthreads();

    auto prefix8 = [&](const unsigned long long* w8, int pos) -> int {
        const int wi = pos >> 6;
        const unsigned long long lowmask = (1ull << (pos & 63)) - 1ull;
        int r = 0;
        #pragma unroll
        for (int q2 = 0; q2 < 8; ++q2) {
            const unsigned long long w = w8[q2];
            r += (q2 < wi) ? __popcll(w) : ((q2 == wi) ? __popcll(w & lowmask) : 0);
        }
        return r;
    };

    const int f = gt || (eq && prefix8(s_eqm, tid) < KrF);
    const unsigned long long fb = __ballot(f);
    if (lane == 0) s_ind[wave] = fb;
    __syncthreads();
    {
        const int cnt = prefix8(s_ind, tid);
        s_c2m[tid] = cnt;
        if (f) s_sep[cnt] = tid;     // cnt in [0,K): unique per separator
    }
    __syncthreads();

    // ---- Phase 3: bpm one-hot FIRST (pure store stream, no load deps)
    {
        float* __restrict__ bpm = out + (size_t)BATCH * MORPH * HID + (size_t)b * (SEQL * MORPH);
        for (int v = tid; v < SEQL * MORPH / 4; v += NTHR) {
            const int l  = v / 6;
            const int qv = v - l * 6;
            const int c  = s_c2m[l];
            const int mb = qv * 4;
            const bool valid = (l < wl);
            f4 o;
            o.x = (valid && c == mb + 0 && mb + 0 < nm) ? 1.0f : 0.0f;
            o.y = (valid && c == mb + 1 && mb + 1 < nm) ? 1.0f : 0.0f;
            o.z = (valid && c == mb + 2 && mb + 2 < nm) ? 1.0f : 0.0f;
            o.w = (valid && c == mb + 3 && mb + 3 < nm) ? 1.0f : 0.0f;
            __builtin_nontemporal_store(o, reinterpret_cast<f4*>(bpm) + v);
        }
    }

    // ---- Phase 4: menc, wave-per-morpheme, 4 independent chains
    for (int m = wave; m < MORPH; m += NWAVE) {
        f4 t = {0.f, 0.f, 0.f, 0.f};
        if (m < nm) {
            const int lo = (m == 0) ? 0 : s_sep[m - 1] + 1;
            const int hi = (m < K) ? s_sep[m] : wl - 1;   // inclusive
            f4 a0 = {0.f,0.f,0.f,0.f}, a1 = {0.f,0.f,0.f,0.f};
            f4 a2 = {0.f,0.f,0.f,0.f}, a3 = {0.f,0.f,0.f,0.f};
            int l = lo;
            for (; l + 3 <= hi; l += 4) {
                a0 += reinterpret_cast<const f4*>(werow + (size_t)(l    ) * HID)[lane];
                a1 += reinterpret_cast<const f4*>(werow + (size_t)(l + 1) * HID)[lane];
                a2 += reinterpret_cast<const f4*>(werow + (size_t)(l + 2) * HID)[lane];
                a3 += reinterpret_cast<const f4*>(werow + (size_t)(l + 3) * HID)[lane];
            }
            for (; l <= hi; ++l)
                a0 += reinterpret_cast<const f4*>(werow + (size_t)l * HID)[lane];
            t = (a0 + a1) + (a2 + a3);
        }
        __builtin_nontemporal_store(
            t, reinterpret_cast<f4*>(out + (size_t)b * (MORPH * HID) + (size_t)m * HID) + lane);
    }
}

extern "C" void kernel_launch(void* const* d_in, const int* in_sizes, int n_in,
                              void* d_out, int out_size, void* d_ws, size_t ws_size,
                              hipStream_t stream) {
    const float* we     = (const float*)d_in[0];
    const int*   wlen   = (const int*)d_in[1];
    const int*   nmorph = (const int*)d_in[2];
    const float* Wv     = (const float*)d_in[3];
    const float* bias   = (const float*)d_in[4];
    float* out = (float*)d_out;

    morphseg_kernel<<<dim3(BATCH), dim3(NTHR), 0, stream>>>(
        we, wlen, nmorph, Wv, bias, out);
}